// Round 11
// baseline (518.434 us; speedup 1.0000x reference)
//
#include <hip/hip_runtime.h>
#include <cstdint>
#include <cstddef>

#define S_  1024
#define B_  4
#define T_  2048
#define H_  16

typedef short     short8 __attribute__((ext_vector_type(8)));
typedef float     f32x4  __attribute__((ext_vector_type(4)));
typedef unsigned short u16x8 __attribute__((ext_vector_type(8)));

__device__ __forceinline__ unsigned short f2b(float f){
  uint32_t x = __builtin_bit_cast(uint32_t, f);
  x = (x + 0x7fffu + ((x >> 16) & 1u)) >> 16;   // RNE
  return (unsigned short)x;
}
__device__ __forceinline__ unsigned short f2bt(float f){   // truncate (1 op)
  return (unsigned short)(__builtin_bit_cast(uint32_t, f) >> 16);
}
__device__ __forceinline__ float b2f(unsigned short u){
  return __builtin_bit_cast(float, ((uint32_t)u) << 16);
}

// async global->LDS, 16B per lane; lds dest must be wave-uniform base
__device__ __forceinline__ void gl_lds16(const unsigned short* g, unsigned short* l){
  __builtin_amdgcn_global_load_lds(
      (const __attribute__((address_space(1))) void*)g,
      (__attribute__((address_space(3))) void*)l,
      16, 0, 0);
}

// ---------------------------------------------------------------------------
// Fused prep: fp32->bf16 converts (x_mem, pos) AND all 4 weight transposes
// in ONE dispatch (block-uniform branch). blk<10240: cvt; else wtrans.
// ---------------------------------------------------------------------------
__global__ __launch_bounds__(256) void prep_all(
    const float* __restrict__ memsrc, const float* __restrict__ inp,
    const float* __restrict__ pos,
    const float* __restrict__ Wkv, const float* __restrict__ Wq,
    const float* __restrict__ Wp,  const float* __restrict__ Wout,
    unsigned short* __restrict__ xb, unsigned short* __restrict__ posb,
    unsigned short* __restrict__ WkvT, unsigned short* __restrict__ WqT,
    unsigned short* __restrict__ WpT,  unsigned short* __restrict__ WoutT)
{
  __shared__ float tile[32][33];
  int blk = blockIdx.x;
  if (blk < 10240){
    int i = (blk * 256 + threadIdx.x) * 4;
    const float* src;
    unsigned short* dst;
    if (i < 8192 * 1024){
      src = (i < 4096 * 1024) ? (memsrc + i) : (inp + (i - 4096 * 1024));
      dst = xb + i;
    } else {
      int i2 = i - 8192 * 1024;
      src = pos + i2;
      dst = posb + i2;
    }
    float4 x = *(const float4*)src;
    ushort4 o;
    o.x = f2b(x.x); o.y = f2b(x.y); o.z = f2b(x.z); o.w = f2b(x.w);
    *(ushort4*)dst = o;
    return;
  }
  blk -= 10240;
  const float* in; unsigned short* out; int C, bx, by;
  if (blk < 2048){ in = Wkv; out = WkvT; C = 2048; bx = blk & 63; by = blk >> 6; }
  else {
    int r = blk - 2048; int wi = r >> 10; r &= 1023;
    C = 1024; bx = r & 31; by = r >> 5;
    in  = (wi == 0) ? Wq  : ((wi == 1) ? Wp  : Wout);
    out = (wi == 0) ? WqT : ((wi == 1) ? WpT : WoutT);
  }
  const int R0 = by * 32, C0 = bx * 32;
  const int t = threadIdx.x;
  const int r = t >> 3, c4 = (t & 7) * 4;
  float4 x = *(const float4*)(in + (size_t)(R0 + r) * C + C0 + c4);
  tile[r][c4+0] = x.x; tile[r][c4+1] = x.y; tile[r][c4+2] = x.z; tile[r][c4+3] = x.w;
  __syncthreads();
  ushort4 o;
  o.x = f2b(tile[c4+0][r]); o.y = f2b(tile[c4+1][r]);
  o.z = f2b(tile[c4+2][r]); o.w = f2b(tile[c4+3][r]);
  *(ushort4*)(out + (size_t)(C0 + r) * 1024 + R0 + c4) = o;
}

// ---------------------------------------------------------------------------
// Transpose V-half of kv into VTg[bh*64 + d][T] (bf16) for PV B-operand.
// ---------------------------------------------------------------------------
__global__ __launch_bounds__(256) void vtrans(
    const unsigned short* __restrict__ kvb, unsigned short* __restrict__ vtg)
{
  __shared__ __align__(16) unsigned short tile[64][72];
  const int t = threadIdx.x;
  const int bh = blockIdx.y;           // b*16+h
  const int b = bh >> 4, h = bh & 15;
  const int t0 = blockIdx.x * 64;
  #pragma unroll
  for (int l = 0; l < 2; ++l){
    int idx = t + l * 256;
    int row = idx >> 3, seg = (idx & 7) * 8;
    u16x8 x = *(const u16x8*)(kvb + ((size_t)(t0 + row) * 4 + b) * 2048 + 1024 + h * 64 + seg);
    *(u16x8*)&tile[row][seg] = x;
  }
  __syncthreads();
  #pragma unroll
  for (int l = 0; l < 2; ++l){
    int idx = t + l * 256;
    int d = idx >> 3, nseg = (idx & 7) * 8;
    u16x8 o;
    #pragma unroll
    for (int j = 0; j < 8; ++j) o[j] = tile[nseg + j][d];
    *(u16x8*)(vtg + ((size_t)bh * 64 + d) * 2048 + t0 + nseg) = o;
  }
}

// LDS layout for async-staged GEMM tiles (m97 pattern, width=16)
#define AS_IDX(row,k) ((((row) >> 3) * 512) + (((k) >> 3) * 64) + (((row) & 7) * 8) + ((k) & 7))

// ---------------------------------------------------------------------------
// Merged projection GEMM: kv (1024 blocks) + q (256) + p (128) in ONE
// dispatch. XCD-aware bijective swizzle (1408 = 8 XCD x 176).
// ---------------------------------------------------------------------------
__global__ __launch_bounds__(256) void gemm_multi(
    const unsigned short* __restrict__ xb,   // (8192,1024)
    const unsigned short* __restrict__ posb, // (2048,1024)
    const unsigned short* __restrict__ WkvT, // (2048,1024)
    const unsigned short* __restrict__ WqT,  // (1024,1024)
    const unsigned short* __restrict__ WpT,  // (1024,1024)
    unsigned short* __restrict__ kvb,        // (8192,2048)
    unsigned short* __restrict__ qbb,        // (4096,1024)
    unsigned short* __restrict__ pbb)        // (2048,1024)
{
  const unsigned short *A, *BT;
  unsigned short* C;
  int N, local;
  int bx = (blockIdx.x & 7) * 176 + (blockIdx.x >> 3);   // XCD swizzle, bijective on [0,1408)
  if (bx < 1024){       A = xb;                       BT = WkvT; C = kvb; N = 2048; local = bx;        }
  else if (bx < 1280){  A = xb + (size_t)4096 * 1024; BT = WqT;  C = qbb; N = 1024; local = bx - 1024; }
  else {                A = posb;                     BT = WpT;  C = pbb; N = 1024; local = bx - 1280; }
  const int nb = N >> 7;
  const int M0 = (local / nb) * 128, N0 = (local % nb) * 128;
  const int K = 1024;

  __shared__ __align__(16) unsigned short As[128 * 64];
  __shared__ __align__(16) unsigned short Bs[128 * 64];
  const int t = threadIdx.x;
  const int w = t >> 6, lane = t & 63, quad = lane >> 4, l16 = lane & 15;
  const int wm = (w >> 1) * 64, wn = (w & 1) * 64;
  const int lr = lane & 7, lcb = lane >> 3;

  f32x4 acc[4][4] = {};

  for (int k0 = 0; k0 < K; k0 += 64){
    __syncthreads();
    #pragma unroll
    for (int i = 0; i < 4; ++i){
      int blk = 4 * w + i;
      gl_lds16(A  + (size_t)(M0 + 8 * blk + lr) * K + k0 + lcb * 8, As + blk * 512);
      gl_lds16(BT + (size_t)(N0 + 8 * blk + lr) * K + k0 + lcb * 8, Bs + blk * 512);
    }
    __syncthreads();
    #pragma unroll
    for (int ks = 0; ks < 2; ++ks){
      short8 af[4], bf[4];
      #pragma unroll
      for (int rt = 0; rt < 4; ++rt)
        af[rt] = *(short8*)&As[AS_IDX(wm + rt * 16 + l16, ks * 32 + quad * 8)];
      #pragma unroll
      for (int ct = 0; ct < 4; ++ct)
        bf[ct] = *(short8*)&Bs[AS_IDX(wn + ct * 16 + l16, ks * 32 + quad * 8)];
      #pragma unroll
      for (int rt = 0; rt < 4; ++rt)
        #pragma unroll
        for (int ct = 0; ct < 4; ++ct)
          acc[rt][ct] = __builtin_amdgcn_mfma_f32_16x16x32_bf16(af[rt], bf[ct], acc[rt][ct], 0, 0, 0);
    }
  }

  #pragma unroll
  for (int rt = 0; rt < 4; ++rt)
    #pragma unroll
    for (int r = 0; r < 4; ++r){
      int row = M0 + wm + rt * 16 + quad * 4 + r;
      #pragma unroll
      for (int ct = 0; ct < 4; ++ct)
        C[(size_t)row * N + N0 + wn + ct * 16 + l16] = f2b(acc[rt][ct][r]);
    }
}

// ---------------------------------------------------------------------------
// Out-projection GEMM, split-K x2. Grid (8,32,2) linearized + XCD swizzle.
// ---------------------------------------------------------------------------
__global__ __launch_bounds__(256) void gemm_outk(
    const unsigned short* __restrict__ A,    // awvb (4096,1024)
    const unsigned short* __restrict__ BT,   // WoutT (1024,1024)
    float* __restrict__ OutP)                // 2 x (4096,1024) fp32
{
  const int K = 1024, N = 1024;
  int lid = blockIdx.x + 8 * (blockIdx.y + 32 * blockIdx.z);   // [0,512)
  int sw  = (lid & 7) * 64 + (lid >> 3);                        // XCD swizzle
  const int N0 = (sw & 7) * 128;
  const int M0 = ((sw >> 3) & 31) * 128;
  const int kz = sw >> 8;
  const int k0s = kz * 512, k0e = k0s + 512;
  float* outF = OutP + (size_t)kz * 4096 * 1024;

  __shared__ __align__(16) unsigned short As[128 * 64];
  __shared__ __align__(16) unsigned short Bs[128 * 64];
  const int t = threadIdx.x;
  const int w = t >> 6, lane = t & 63, quad = lane >> 4, l16 = lane & 15;
  const int wm = (w >> 1) * 64, wn = (w & 1) * 64;
  const int lr = lane & 7, lcb = lane >> 3;

  f32x4 acc[4][4] = {};

  for (int k0 = k0s; k0 < k0e; k0 += 64){
    __syncthreads();
    #pragma unroll
    for (int i = 0; i < 4; ++i){
      int blk = 4 * w + i;
      gl_lds16(A  + (size_t)(M0 + 8 * blk + lr) * K + k0 + lcb * 8, As + blk * 512);
      gl_lds16(BT + (size_t)(N0 + 8 * blk + lr) * K + k0 + lcb * 8, Bs + blk * 512);
    }
    __syncthreads();
    #pragma unroll
    for (int ks = 0; ks < 2; ++ks){
      short8 af[4], bf[4];
      #pragma unroll
      for (int rt = 0; rt < 4; ++rt)
        af[rt] = *(short8*)&As[AS_IDX(wm + rt * 16 + l16, ks * 32 + quad * 8)];
      #pragma unroll
      for (int ct = 0; ct < 4; ++ct)
        bf[ct] = *(short8*)&Bs[AS_IDX(wn + ct * 16 + l16, ks * 32 + quad * 8)];
      #pragma unroll
      for (int rt = 0; rt < 4; ++rt)
        #pragma unroll
        for (int ct = 0; ct < 4; ++ct)
          acc[rt][ct] = __builtin_amdgcn_mfma_f32_16x16x32_bf16(af[rt], bf[ct], acc[rt][ct], 0, 0, 0);
    }
  }

  #pragma unroll
  for (int rt = 0; rt < 4; ++rt)
    #pragma unroll
    for (int r = 0; r < 4; ++r){
      int row = M0 + wm + rt * 16 + quad * 4 + r;
      #pragma unroll
      for (int ct = 0; ct < 4; ++ct)
        outF[(size_t)row * N + N0 + wn + ct * 16 + l16] = acc[rt][ct][r];
    }
}

// ---------------------------------------------------------------------------
// MFMA flash attention, fused Transformer-XL rel-shift, split-j x2.
// R10 structure (best measured: 139.2us) + pack-2 bpermute: the rel-shift
// pull moves TWO windows per ds_bpermute as 2xbf16 packed in one dword
// (source lane packs racc5[base+ct], racc5[base+ct+1]; base=psel) ->
// 8 bpermutes/wave/chunk instead of 16. Pos values go through bf16
// truncation, same precision as the pre-R10 Sc scatter path.
// LDS = 8K (Kc) + 8K (VT) + 16K (Pw) + 8K (SP) = 40960 B.
// __launch_bounds__(256,3): no scratch ((256,4) spills).
// ---------------------------------------------------------------------------
#define SP_IX(gm,n) ((gm) * 64 + ((n) ^ (((gm) & 12) << 2)))

__global__ __launch_bounds__(256, 3) void attn_mfma(
    const unsigned short* __restrict__ qb,   // (4096,1024) bf16
    const unsigned short* __restrict__ kvb,  // (8192,2048) bf16 [k|v]
    const unsigned short* __restrict__ pbm,  // (2048,1024) bf16
    const unsigned short* __restrict__ vtg,  // (64*64, 2048) bf16 V^T per (b,h)
    const float* __restrict__ ub, const float* __restrict__ vb,
    unsigned short* __restrict__ opart,      // 2 x (4096,1024) bf16 partials
    float* __restrict__ lpart)               // 2 x (4096,16) fp32 partials
{
  __shared__ __align__(16) unsigned short Kc[64 * 64];   // swizzled K tile
  __shared__ __align__(16) unsigned short VT[64 * 64];   // swizzled V^T tile
  __shared__ __align__(16) unsigned short Pw[128 * 64];  // swizzled pos ring (2 halves)
  __shared__ __align__(16) unsigned short SP[64 * 64];   // P (exp) buffer, swizzled

  const int t = threadIdx.x;
  const int i0 = blockIdx.x * 64;
  const int bh = blockIdx.y;
  const int jh = blockIdx.z;
  const int b = bh >> 4, h = bh & 15;
  const int w = t >> 6, lane = t & 63, quad = lane >> 4, l16 = lane & 15;
  const int colbase = h * 64 + quad * 8;
  const int ctLo = 3 - w;                    // wave-trimmed window range [ctLo, ctLo+4]

  const float SCQ = 0.1803368801f;           // 0.125 * log2(e)
  const float EOF_ = 23.0831206f;            // 16 * log2(e)

  // ---- register A-fragments: qu[ks], qv[cs][ks], pre-scaled by SCQ ----
  short8 qu[2], qv[2][2];
  #pragma unroll
  for (int cs = 0; cs < 2; ++cs){
    int gr = i0 + 16 * w + l16 + cs;         // gr==1024 possible: harmless
    #pragma unroll
    for (int ks = 0; ks < 2; ++ks){
      u16x8 q8 = *(const u16x8*)(qb + ((size_t)gr * 4 + b) * 1024 + colbase + ks * 32);
      #pragma unroll
      for (int j = 0; j < 8; ++j){
        float f = b2f(q8[j]);
        qv[cs][ks][j] = (short)f2b((f + vb[colbase + ks * 32 + j]) * SCQ);
        if (cs == 0) qu[ks][j] = (short)f2b((f + ub[colbase + ks * 32 + j]) * SCQ);
      }
    }
  }

  f32x4 oacc[4] = {};                        // [d-tile], rows = quad*4+r
  float lsum[4] = {0.f, 0.f, 0.f, 0.f};

  // staging prefetch registers
  u16x8 pk[2], pv2[2], pp[4];

  auto loadKV = [&](int jc){
    const int j0 = jc * 64;
    #pragma unroll
    for (int l = 0; l < 2; ++l){
      int idx = t + l * 256;
      int row = idx >> 3, cb = idx & 7;
      pk[l]  = *(const u16x8*)(kvb + ((size_t)(j0 + row) * 4 + b) * 2048 + h * 64 + cb * 8);
      pv2[l] = *(const u16x8*)(vtg + ((size_t)bh * 64 + row) * 2048 + j0 + cb * 8);
    }
  };

  auto loadPPfull = [&](int jc){             // full 128-row window (prologue)
    const int D = jc * 64 - i0;
    #pragma unroll
    for (int l = 0; l < 4; ++l){
      int idx = t + l * 256;
      int row = idx >> 3, cb = idx & 7;
      int pr;
      if (D <= 960)          pr = D + 960 + row;
      else if (D == 1024)    pr = (row < 64) ? (1984 + row) : (row - 65);
      else                   pr = D - 1089 + row;
      u16x8 x;
      if (pr >= 0 && pr < T_){
        x = *(const u16x8*)(pbm + (size_t)pr * 1024 + h * 64 + cb * 8);
      } else {
        for (int j = 0; j < 8; ++j) x[j] = 0;
      }
      pp[l] = x;
    }
  };

  auto loadPPhalf = [&](int jc){             // rows [64,128) of window(jc)
    const int D = jc * 64 - i0;
    #pragma unroll
    for (int l = 0; l < 2; ++l){
      int idx = t + l * 256;
      int rowh = idx >> 3, cb = idx & 7;
      int pr = (D <= 960) ? (D + 1024 + rowh) : (D - 1025 + rowh);
      u16x8 x;
      if (pr >= 0 && pr < T_){
        x = *(const u16x8*)(pbm + (size_t)pr * 1024 + h * 64 + cb * 8);
      } else {
        for (int j = 0; j < 8; ++j) x[j] = 0;
      }
      pp[l] = x;
    }
  };

  auto storeKV = [&](){
    #pragma unroll
    for (int l = 0; l < 2; ++l){
      int idx = t + l * 256;
      int row = idx >> 3, cb = idx & 7;
      int sw = (cb ^ (row & 7)) * 8;
      *(u16x8*)&Kc[row * 64 + sw] = pk[l];
      *(u16x8*)&VT[row * 64 + sw] = pv2[l];
    }
  };
  auto storePPfull = [&](){
    #pragma unroll
    for (int l = 0; l < 4; ++l){
      int idx = t + l * 256;
      int row = idx >> 3, cb = idx & 7;
      *(u16x8*)&Pw[row * 64 + ((cb ^ (row & 7)) * 8)] = pp[l];
    }
  };
  auto storePPhalf = [&](int physh){
    #pragma unroll
    for (int l = 0; l < 2; ++l){
      int idx = t + l * 256;
      int rowh = idx >> 3, cb = idx & 7;
      *(u16x8*)&Pw[(physh * 64 + rowh) * 64 + ((cb ^ (rowh & 7)) * 8)] = pp[l];
    }
  };

  const int jcs = jh * 16, jce = jcs + 16;
  loadKV(jcs);
  loadPPfull(jcs);
  int par = 0;                               // (jc - jcs) & 1

  // per-r bpermute indices & window-select predicates (chunk-invariant)
  int pidx[4];
  int pbase[4];
  #pragma unroll
  for (int r = 0; r < 4; ++r){
    pidx[r]  = ((lane & 48) + ((l16 + 15 - 4 * quad - r) & 15)) * 4;
    pbase[r] = ((l16 + 4 * quad + r) < 15) ? 1 : 0;
  }

  #pragma unroll 1
  for (int jc = jcs; jc < jce; ++jc){
    const int D = jc * 64 - i0;

    __syncthreads();                         // (1) prev chunk's LDS reads done
    storeKV();
    if (jc == jcs) storePPfull(); else storePPhalf(1 ^ par);
    if (jc + 1 < jce){ loadKV(jc + 1); loadPPhalf(jc + 1); }   // prefetch next
    __syncthreads();                         // (2) staging visible

    // ---- pos scores: 5 trimmed windows kept in registers ----
    f32x4 racc5[5];
    #pragma unroll
    for (int ci = 0; ci < 5; ++ci){
      int ct = ctLo + ci;
      int cs = (D <= 960) ? 0 : ((D >= 1088) ? 1 : ((ct >= 4) ? 1 : 0));
      f32x4 racc = {};
      #pragma unroll
      for (int ks = 0; ks < 2; ++ks){
        int rr = ct * 16 + l16;
        int prow = ((rr >> 6) ^ par) * 64 + (rr & 63);
        short8 bf = *(short8*)&Pw[prow * 64 + (((ks * 4 + quad) ^ (rr & 7)) * 8)];
        racc = __builtin_amdgcn_mfma_f32_16x16x32_bf16(qv[cs][ks], bf, racc, 0, 0, 0);
      }
      racc5[ci] = racc;
    }

    // ---- content scores ----
    f32x4 cacc[4] = {};
    #pragma unroll
    for (int ks = 0; ks < 2; ++ks){
      #pragma unroll
      for (int ct = 0; ct < 4; ++ct){
        int rr = ct * 16 + l16;
        short8 bf = *(short8*)&Kc[rr * 64 + (((ks * 4 + quad) ^ (rr & 7)) * 8)];
        cacc[ct] = __builtin_amdgcn_mfma_f32_16x16x32_bf16(qu[ks], bf, cacc[ct], 0, 0, 0);
      }
    }

    // ---- softmax with pack-2 bpermute rel-shift pull ----
    #pragma unroll
    for (int r = 0; r < 4; ++r){
      int gm = 16 * w + quad * 4 + r;
      int bse = pbase[r];
      uint32_t pa = (uint32_t)f2bt(racc5[bse + 0][r]) | ((uint32_t)f2bt(racc5[bse + 1][r]) << 16);
      uint32_t pb = (uint32_t)f2bt(racc5[bse + 2][r]) | ((uint32_t)f2bt(racc5[bse + 3][r]) << 16);
      uint32_t ra = (uint32_t)__builtin_amdgcn_ds_bpermute(pidx[r], (int)pa);
      uint32_t rb = (uint32_t)__builtin_amdgcn_ds_bpermute(pidx[r], (int)pb);
      float pos01[2] = { b2f((unsigned short)(ra & 0xffffu)), b2f((unsigned short)(ra >> 16)) };
      float pos23[2] = { b2f((unsigned short)(rb & 0xffffu)), b2f((unsigned short)(rb >> 16)) };
      #pragma unroll
      for (int ct = 0; ct < 4; ++ct){
        float posv = (ct < 2) ? pos01[ct] : pos23[ct - 2];
        float s = cacc[ct][r] + posv;
        float e = __builtin_amdgcn_exp2f(s - EOF_);
        lsum[r] += e;
        SP[SP_IX(gm, ct * 16 + l16)] = f2bt(e);
      }
    }

    // ---- PV: A-frag from own-wave SP rows, B-frag from swizzled VT ----
    #pragma unroll
    for (int ks = 0; ks < 2; ++ks){
      short8 af = *(short8*)&SP[SP_IX(16 * w + l16, ks * 32 + quad * 8)];
      #pragma unroll
      for (int dt = 0; dt < 4; ++dt){
        int rr = dt * 16 + l16;
        short8 bf = *(short8*)&VT[rr * 64 + (((ks * 4 + quad) ^ (rr & 7)) * 8)];
        oacc[dt] = __builtin_amdgcn_mfma_f32_16x16x32_bf16(af, bf, oacc[dt], 0, 0, 0);
      }
    }

    par ^= 1;
  }

  // ---- epilogue: reduce row sums, store bf16 O-partial + fp32 l-partial ----
  unsigned short* ob = opart + (size_t)jh * 4096 * 1024;
  float* lb = lpart + (size_t)jh * 4096 * 16;
  #pragma unroll
  for (int r = 0; r < 4; ++r){
    float red = lsum[r];
    #pragma unroll
    for (int mk = 1; mk < 16; mk <<= 1)
      red += __shfl_xor(red, mk, 64);
    int srow = i0 + 16 * w + quad * 4 + r;
    int grow = srow * 4 + b;
    #pragma unroll
    for (int dt = 0; dt < 4; ++dt)
      ob[(size_t)grow * 1024 + h * 64 + dt * 16 + l16] = f2bt(oacc[dt][r]);
    if (l16 == 0) lb[(size_t)grow * 16 + h] = red;
  }
}

// ---------------------------------------------------------------------------
// Combine the two j-half partials: awv = (O0 + O1) / (l0 + l1), bf16 out.
// ---------------------------------------------------------------------------
__global__ __launch_bounds__(256) void attn_combine(
    const unsigned short* __restrict__ opart, const float* __restrict__ lpart,
    unsigned short* __restrict__ awvb)
{
  const int grow = blockIdx.x, t = threadIdx.x;
  const int d4 = t * 4, h = t >> 4;
  float l = lpart[(size_t)grow * 16 + h] + lpart[(size_t)4096 * 16 + grow * 16 + h];
  float inv = 1.f / l;
  ushort4 a = *(const ushort4*)(opart + (size_t)grow * 1024 + d4);
  ushort4 c = *(const ushort4*)(opart + (size_t)4096 * 1024 + grow * 1024 + d4);
  ushort4 o;
  o.x = f2bt((b2f(a.x) + b2f(c.x)) * inv);
  o.y = f2bt((b2f(a.y) + b2f(c.y)) * inv);
  o.z = f2bt((b2f(a.z) + b2f(c.z)) * inv);
  o.w = f2bt((b2f(a.w) + b2f(c.w)) * inv);
  *(ushort4*)(awvb + (size_t)grow * 1024 + d4) = o;
}

// ---------------------------------------------------------------------------
// LayerNorm over last dim: out = LN(input + P0 + P1) * g + b  (fp32 out).
// ---------------------------------------------------------------------------
__global__ __launch_bounds__(256) void ln2_kernel(
    const float* __restrict__ inp, const float* __restrict__ OutP,
    const float* __restrict__ g, const float* __restrict__ bb,
    float* __restrict__ out)
{
  const int row = blockIdx.x, t = threadIdx.x;
  float4 x  = *(const float4*)(inp  + (size_t)row * 1024 + t * 4);
  float4 p0 = *(const float4*)(OutP + (size_t)row * 1024 + t * 4);
  float4 p1 = *(const float4*)(OutP + (size_t)4096 * 1024 + row * 1024 + t * 4);
  x.x += p0.x + p1.x; x.y += p0.y + p1.y; x.z += p0.z + p1.z; x.w += p0.w + p1.w;
  float s  = x.x + x.y + x.z + x.w;
  float s2 = x.x*x.x + x.y*x.y + x.z*x.z + x.w*x.w;
  #pragma unroll
  for (int o = 32; o > 0; o >>= 1){
    s  += __shfl_down(s, o);
    s2 += __shfl_down(s2, o);
  }
  __shared__ float rs[4], rs2[4];
  int w = t >> 6, lane = t & 63;
  if (lane == 0){ rs[w] = s; rs2[w] = s2; }
  __syncthreads();
  s  = rs[0] + rs[1] + rs[2] + rs[3];
  s2 = rs2[0] + rs2[1] + rs2[2] + rs2[3];
  float mu   = s * (1.f/1024.f);
  float var  = s2 * (1.f/1024.f) - mu*mu;
  float rstd = rsqrtf(var + 1e-5f);
  float4 gg = *(const float4*)(g + t*4);
  float4 bv = *(const float4*)(bb + t*4);
  float4 o;
  o.x = (x.x - mu)*rstd*gg.x + bv.x;
  o.y = (x.y - mu)*rstd*gg.y + bv.y;
  o.z = (x.z - mu)*rstd*gg.z + bv.z;
  o.w = (x.w - mu)*rstd*gg.w + bv.w;
  *(float4*)(out + (size_t)row * 1024 + t * 4) = o;
}

extern "C" void kernel_launch(void* const* d_in, const int* in_sizes, int n_in,
                              void* d_out, int out_size, void* d_ws, size_t ws_size,
                              hipStream_t stream) {
  (void)in_sizes; (void)n_in; (void)out_size; (void)ws_size;
  const float* input_ = (const float*)d_in[0];
  const float* pos    = (const float*)d_in[1];
  const float* mem    = (const float*)d_in[2];
  const float* u      = (const float*)d_in[3];
  const float* v      = (const float*)d_in[4];
  const float* Wkv    = (const float*)d_in[5];
  const float* Wq     = (const float*)d_in[6];
  const float* Wp     = (const float*)d_in[7];
  const float* Wout   = (const float*)d_in[8];
  const float* lng    = (const float*)d_in[9];
  const float* lnb    = (const float*)d_in[10];
  float* out = (float*)d_out;

  unsigned short* ws   = (unsigned short*)d_ws;
  unsigned short* xb    = ws;                               // 8192*1024
  unsigned short* posb  = xb    + (size_t)8192*1024;        // 2048*1024
  unsigned short* WkvT  = posb  + (size_t)2048*1024;        // 2048*1024
  unsigned short* WqT   = WkvT  + (size_t)2048*1024;        // 1024*1024
  unsigned short* WpT   = WqT   + (size_t)1024*1024;        // 1024*1024
  unsigned short* WoutT = WpT   + (size_t)1024*1024;        // 1024*1024
  unsigned short* kvb   = WoutT + (size_t)1024*1024;        // 8192*2048
  unsigned short* qbb   = kvb   + (size_t)8192*2048;        // 4096*1024
  unsigned short* pbb   = qbb   + (size_t)4096*1024;        // 2048*1024
  unsigned short* vtg   = pbb   + (size_t)2048*1024;        // 4096*2048
  unsigned short* awvb  = vtg   + (size_t)4096*2048;        // 4096*1024

  // overlays (lifetime-disjoint):
  unsigned short* opart = xb;                 // 2 x 4096*1024 bf16; xb dead after gemm_multi
  float*          lpart = (float*)posb;       // 2 x 4096*16 fp32;  posb dead after gemm_multi
  float*          OutP  = (float*)kvb;        // 2 x 4096*1024 fp32; kvb dead after attn

  // fused prep: bf16 converts + all weight transposes in one dispatch
  prep_all<<<15360, 256, 0, stream>>>(mem, input_, pos, Wkv, Wq, Wp, Wout,
                                      xb, posb, WkvT, WqT, WpT, WoutT);

  // merged projections (kv + q + p) in one dispatch
  gemm_multi<<<1408, 256, 0, stream>>>(xb, posb, WkvT, WqT, WpT, kvb, qbb, pbb);

  // V transpose for PV B-operand
  vtrans<<<dim3(32, 64), 256, 0, stream>>>(kvb, vtg);

  // fused rel-shift MFMA flash attention, split-j x2
  attn_mfma<<<dim3(16, 64, 2), 256, 0, stream>>>(qbb, kvb, pbb, vtg, u, v, opart, lpart);
  attn_combine<<<4096, 256, 0, stream>>>(opart, lpart, awvb);

  // out-projection, split-K x2 (fp32 partials), then fused residual+LN
  gemm_outk<<<dim3(8, 32, 2), 256, 0, stream>>>(awvb, WoutT, OutP);
  ln2_kernel<<<4096, 256, 0, stream>>>(input_, OutP, lng, lnb, out);
}

// Round 12
// 379.706 us; speedup vs baseline: 1.3654x; 1.3654x over previous
//
#include <hip/hip_runtime.h>
#include <cstdint>
#include <cstddef>

#define S_  1024
#define B_  4
#define T_  2048
#define H_  16

typedef short     short8 __attribute__((ext_vector_type(8)));
typedef float     f32x4  __attribute__((ext_vector_type(4)));
typedef unsigned short u16x8 __attribute__((ext_vector_type(8)));

__device__ __forceinline__ unsigned short f2b(float f){
  uint32_t x = __builtin_bit_cast(uint32_t, f);
  x = (x + 0x7fffu + ((x >> 16) & 1u)) >> 16;   // RNE
  return (unsigned short)x;
}
__device__ __forceinline__ unsigned short f2bt(float f){   // truncate (1 op)
  return (unsigned short)(__builtin_bit_cast(uint32_t, f) >> 16);
}
__device__ __forceinline__ float b2f(unsigned short u){
  return __builtin_bit_cast(float, ((uint32_t)u) << 16);
}

// async global->LDS, 16B per lane; lds dest must be wave-uniform base
__device__ __forceinline__ void gl_lds16(const unsigned short* g, unsigned short* l){
  __builtin_amdgcn_global_load_lds(
      (const __attribute__((address_space(1))) void*)g,
      (__attribute__((address_space(3))) void*)l,
      16, 0, 0);
}

// ---------------------------------------------------------------------------
// Fused prep: fp32->bf16 converts (x_mem, pos) AND all 4 weight transposes
// in ONE dispatch (block-uniform branch). blk<10240: cvt; else wtrans.
// ---------------------------------------------------------------------------
__global__ __launch_bounds__(256) void prep_all(
    const float* __restrict__ memsrc, const float* __restrict__ inp,
    const float* __restrict__ pos,
    const float* __restrict__ Wkv, const float* __restrict__ Wq,
    const float* __restrict__ Wp,  const float* __restrict__ Wout,
    unsigned short* __restrict__ xb, unsigned short* __restrict__ posb,
    unsigned short* __restrict__ WkvT, unsigned short* __restrict__ WqT,
    unsigned short* __restrict__ WpT,  unsigned short* __restrict__ WoutT)
{
  __shared__ float tile[32][33];
  int blk = blockIdx.x;
  if (blk < 10240){
    int i = (blk * 256 + threadIdx.x) * 4;
    const float* src;
    unsigned short* dst;
    if (i < 8192 * 1024){
      src = (i < 4096 * 1024) ? (memsrc + i) : (inp + (i - 4096 * 1024));
      dst = xb + i;
    } else {
      int i2 = i - 8192 * 1024;
      src = pos + i2;
      dst = posb + i2;
    }
    float4 x = *(const float4*)src;
    ushort4 o;
    o.x = f2b(x.x); o.y = f2b(x.y); o.z = f2b(x.z); o.w = f2b(x.w);
    *(ushort4*)dst = o;
    return;
  }
  blk -= 10240;
  const float* in; unsigned short* out; int C, bx, by;
  if (blk < 2048){ in = Wkv; out = WkvT; C = 2048; bx = blk & 63; by = blk >> 6; }
  else {
    int r = blk - 2048; int wi = r >> 10; r &= 1023;
    C = 1024; bx = r & 31; by = r >> 5;
    in  = (wi == 0) ? Wq  : ((wi == 1) ? Wp  : Wout);
    out = (wi == 0) ? WqT : ((wi == 1) ? WpT : WoutT);
  }
  const int R0 = by * 32, C0 = bx * 32;
  const int t = threadIdx.x;
  const int r = t >> 3, c4 = (t & 7) * 4;
  float4 x = *(const float4*)(in + (size_t)(R0 + r) * C + C0 + c4);
  tile[r][c4+0] = x.x; tile[r][c4+1] = x.y; tile[r][c4+2] = x.z; tile[r][c4+3] = x.w;
  __syncthreads();
  ushort4 o;
  o.x = f2b(tile[c4+0][r]); o.y = f2b(tile[c4+1][r]);
  o.z = f2b(tile[c4+2][r]); o.w = f2b(tile[c4+3][r]);
  *(ushort4*)(out + (size_t)(C0 + r) * 1024 + R0 + c4) = o;
}

// ---------------------------------------------------------------------------
// Transpose V-half of kv into VTg[bh*64 + d][T] (bf16) for PV B-operand.
// ---------------------------------------------------------------------------
__global__ __launch_bounds__(256) void vtrans(
    const unsigned short* __restrict__ kvb, unsigned short* __restrict__ vtg)
{
  __shared__ __align__(16) unsigned short tile[64][72];
  const int t = threadIdx.x;
  const int bh = blockIdx.y;           // b*16+h
  const int b = bh >> 4, h = bh & 15;
  const int t0 = blockIdx.x * 64;
  #pragma unroll
  for (int l = 0; l < 2; ++l){
    int idx = t + l * 256;
    int row = idx >> 3, seg = (idx & 7) * 8;
    u16x8 x = *(const u16x8*)(kvb + ((size_t)(t0 + row) * 4 + b) * 2048 + 1024 + h * 64 + seg);
    *(u16x8*)&tile[row][seg] = x;
  }
  __syncthreads();
  #pragma unroll
  for (int l = 0; l < 2; ++l){
    int idx = t + l * 256;
    int d = idx >> 3, nseg = (idx & 7) * 8;
    u16x8 o;
    #pragma unroll
    for (int j = 0; j < 8; ++j) o[j] = tile[nseg + j][d];
    *(u16x8*)(vtg + ((size_t)bh * 64 + d) * 2048 + t0 + nseg) = o;
  }
}

// LDS layout for async-staged GEMM tiles (m97 pattern, width=16)
#define AS_IDX(row,k) ((((row) >> 3) * 512) + (((k) >> 3) * 64) + (((row) & 7) * 8) + ((k) & 7))

// ---------------------------------------------------------------------------
// Merged projection GEMM: kv (1024 blocks) + q (256) + p (128) in ONE
// dispatch. XCD-aware bijective swizzle (1408 = 8 XCD x 176).
// ---------------------------------------------------------------------------
__global__ __launch_bounds__(256) void gemm_multi(
    const unsigned short* __restrict__ xb,   // (8192,1024)
    const unsigned short* __restrict__ posb, // (2048,1024)
    const unsigned short* __restrict__ WkvT, // (2048,1024)
    const unsigned short* __restrict__ WqT,  // (1024,1024)
    const unsigned short* __restrict__ WpT,  // (1024,1024)
    unsigned short* __restrict__ kvb,        // (8192,2048)
    unsigned short* __restrict__ qbb,        // (4096,1024)
    unsigned short* __restrict__ pbb)        // (2048,1024)
{
  const unsigned short *A, *BT;
  unsigned short* C;
  int N, local;
  int bx = (blockIdx.x & 7) * 176 + (blockIdx.x >> 3);   // XCD swizzle, bijective on [0,1408)
  if (bx < 1024){       A = xb;                       BT = WkvT; C = kvb; N = 2048; local = bx;        }
  else if (bx < 1280){  A = xb + (size_t)4096 * 1024; BT = WqT;  C = qbb; N = 1024; local = bx - 1024; }
  else {                A = posb;                     BT = WpT;  C = pbb; N = 1024; local = bx - 1280; }
  const int nb = N >> 7;
  const int M0 = (local / nb) * 128, N0 = (local % nb) * 128;
  const int K = 1024;

  __shared__ __align__(16) unsigned short As[128 * 64];
  __shared__ __align__(16) unsigned short Bs[128 * 64];
  const int t = threadIdx.x;
  const int w = t >> 6, lane = t & 63, quad = lane >> 4, l16 = lane & 15;
  const int wm = (w >> 1) * 64, wn = (w & 1) * 64;
  const int lr = lane & 7, lcb = lane >> 3;

  f32x4 acc[4][4] = {};

  for (int k0 = 0; k0 < K; k0 += 64){
    __syncthreads();
    #pragma unroll
    for (int i = 0; i < 4; ++i){
      int blk = 4 * w + i;
      gl_lds16(A  + (size_t)(M0 + 8 * blk + lr) * K + k0 + lcb * 8, As + blk * 512);
      gl_lds16(BT + (size_t)(N0 + 8 * blk + lr) * K + k0 + lcb * 8, Bs + blk * 512);
    }
    __syncthreads();
    #pragma unroll
    for (int ks = 0; ks < 2; ++ks){
      short8 af[4], bf[4];
      #pragma unroll
      for (int rt = 0; rt < 4; ++rt)
        af[rt] = *(short8*)&As[AS_IDX(wm + rt * 16 + l16, ks * 32 + quad * 8)];
      #pragma unroll
      for (int ct = 0; ct < 4; ++ct)
        bf[ct] = *(short8*)&Bs[AS_IDX(wn + ct * 16 + l16, ks * 32 + quad * 8)];
      #pragma unroll
      for (int rt = 0; rt < 4; ++rt)
        #pragma unroll
        for (int ct = 0; ct < 4; ++ct)
          acc[rt][ct] = __builtin_amdgcn_mfma_f32_16x16x32_bf16(af[rt], bf[ct], acc[rt][ct], 0, 0, 0);
    }
  }

  #pragma unroll
  for (int rt = 0; rt < 4; ++rt)
    #pragma unroll
    for (int r = 0; r < 4; ++r){
      int row = M0 + wm + rt * 16 + quad * 4 + r;
      #pragma unroll
      for (int ct = 0; ct < 4; ++ct)
        C[(size_t)row * N + N0 + wn + ct * 16 + l16] = f2b(acc[rt][ct][r]);
    }
}

// ---------------------------------------------------------------------------
// Out-projection GEMM, split-K x2. Grid (8,32,2) linearized + XCD swizzle.
// ---------------------------------------------------------------------------
__global__ __launch_bounds__(256) void gemm_outk(
    const unsigned short* __restrict__ A,    // awvb (4096,1024)
    const unsigned short* __restrict__ BT,   // WoutT (1024,1024)
    float* __restrict__ OutP)                // 2 x (4096,1024) fp32
{
  const int K = 1024, N = 1024;
  int lid = blockIdx.x + 8 * (blockIdx.y + 32 * blockIdx.z);   // [0,512)
  int sw  = (lid & 7) * 64 + (lid >> 3);                        // XCD swizzle
  const int N0 = (sw & 7) * 128;
  const int M0 = ((sw >> 3) & 31) * 128;
  const int kz = sw >> 8;
  const int k0s = kz * 512, k0e = k0s + 512;
  float* outF = OutP + (size_t)kz * 4096 * 1024;

  __shared__ __align__(16) unsigned short As[128 * 64];
  __shared__ __align__(16) unsigned short Bs[128 * 64];
  const int t = threadIdx.x;
  const int w = t >> 6, lane = t & 63, quad = lane >> 4, l16 = lane & 15;
  const int wm = (w >> 1) * 64, wn = (w & 1) * 64;
  const int lr = lane & 7, lcb = lane >> 3;

  f32x4 acc[4][4] = {};

  for (int k0 = k0s; k0 < k0e; k0 += 64){
    __syncthreads();
    #pragma unroll
    for (int i = 0; i < 4; ++i){
      int blk = 4 * w + i;
      gl_lds16(A  + (size_t)(M0 + 8 * blk + lr) * K + k0 + lcb * 8, As + blk * 512);
      gl_lds16(BT + (size_t)(N0 + 8 * blk + lr) * K + k0 + lcb * 8, Bs + blk * 512);
    }
    __syncthreads();
    #pragma unroll
    for (int ks = 0; ks < 2; ++ks){
      short8 af[4], bf[4];
      #pragma unroll
      for (int rt = 0; rt < 4; ++rt)
        af[rt] = *(short8*)&As[AS_IDX(wm + rt * 16 + l16, ks * 32 + quad * 8)];
      #pragma unroll
      for (int ct = 0; ct < 4; ++ct)
        bf[ct] = *(short8*)&Bs[AS_IDX(wn + ct * 16 + l16, ks * 32 + quad * 8)];
      #pragma unroll
      for (int rt = 0; rt < 4; ++rt)
        #pragma unroll
        for (int ct = 0; ct < 4; ++ct)
          acc[rt][ct] = __builtin_amdgcn_mfma_f32_16x16x32_bf16(af[rt], bf[ct], acc[rt][ct], 0, 0, 0);
    }
  }

  #pragma unroll
  for (int rt = 0; rt < 4; ++rt)
    #pragma unroll
    for (int r = 0; r < 4; ++r){
      int row = M0 + wm + rt * 16 + quad * 4 + r;
      #pragma unroll
      for (int ct = 0; ct < 4; ++ct)
        outF[(size_t)row * N + N0 + wn + ct * 16 + l16] = acc[rt][ct][r];
    }
}

// ---------------------------------------------------------------------------
// MFMA flash attention, fused Transformer-XL rel-shift, split-j x2.
// R10 structure (139.2us) + pack-2 bpermute with STATIC racc5 indexing:
// window selects are materialized via compile-time-indexed cndmasks
// (w0..w3 = psel ? racc5[k+1] : racc5[k]) BEFORE packing — R11's runtime
// racc5[bse+ct] indexing sent the array to scratch (rule #20: +37MB
// WRITE_SIZE, 2x slowdown). 8 bpermutes/wave/chunk instead of 16.
// LDS = 8K (Kc) + 8K (VT) + 16K (Pw) + 8K (SP) = 40960 B.
// __launch_bounds__(256,3): no scratch ((256,4) spills).
// ---------------------------------------------------------------------------
#define SP_IX(gm,n) ((gm) * 64 + ((n) ^ (((gm) & 12) << 2)))

__global__ __launch_bounds__(256, 3) void attn_mfma(
    const unsigned short* __restrict__ qb,   // (4096,1024) bf16
    const unsigned short* __restrict__ kvb,  // (8192,2048) bf16 [k|v]
    const unsigned short* __restrict__ pbm,  // (2048,1024) bf16
    const unsigned short* __restrict__ vtg,  // (64*64, 2048) bf16 V^T per (b,h)
    const float* __restrict__ ub, const float* __restrict__ vb,
    unsigned short* __restrict__ opart,      // 2 x (4096,1024) bf16 partials
    float* __restrict__ lpart)               // 2 x (4096,16) fp32 partials
{
  __shared__ __align__(16) unsigned short Kc[64 * 64];   // swizzled K tile
  __shared__ __align__(16) unsigned short VT[64 * 64];   // swizzled V^T tile
  __shared__ __align__(16) unsigned short Pw[128 * 64];  // swizzled pos ring (2 halves)
  __shared__ __align__(16) unsigned short SP[64 * 64];   // P (exp) buffer, swizzled

  const int t = threadIdx.x;
  const int i0 = blockIdx.x * 64;
  const int bh = blockIdx.y;
  const int jh = blockIdx.z;
  const int b = bh >> 4, h = bh & 15;
  const int w = t >> 6, lane = t & 63, quad = lane >> 4, l16 = lane & 15;
  const int colbase = h * 64 + quad * 8;
  const int ctLo = 3 - w;                    // wave-trimmed window range [ctLo, ctLo+4]

  const float SCQ = 0.1803368801f;           // 0.125 * log2(e)
  const float EOF_ = 23.0831206f;            // 16 * log2(e)

  // ---- register A-fragments: qu[ks], qv[cs][ks], pre-scaled by SCQ ----
  short8 qu[2], qv[2][2];
  #pragma unroll
  for (int cs = 0; cs < 2; ++cs){
    int gr = i0 + 16 * w + l16 + cs;         // gr==1024 possible: harmless
    #pragma unroll
    for (int ks = 0; ks < 2; ++ks){
      u16x8 q8 = *(const u16x8*)(qb + ((size_t)gr * 4 + b) * 1024 + colbase + ks * 32);
      #pragma unroll
      for (int j = 0; j < 8; ++j){
        float f = b2f(q8[j]);
        qv[cs][ks][j] = (short)f2b((f + vb[colbase + ks * 32 + j]) * SCQ);
        if (cs == 0) qu[ks][j] = (short)f2b((f + ub[colbase + ks * 32 + j]) * SCQ);
      }
    }
  }

  f32x4 oacc[4] = {};                        // [d-tile], rows = quad*4+r
  float lsum[4] = {0.f, 0.f, 0.f, 0.f};

  // staging prefetch registers
  u16x8 pk[2], pv2[2], pp[4];

  auto loadKV = [&](int jc){
    const int j0 = jc * 64;
    #pragma unroll
    for (int l = 0; l < 2; ++l){
      int idx = t + l * 256;
      int row = idx >> 3, cb = idx & 7;
      pk[l]  = *(const u16x8*)(kvb + ((size_t)(j0 + row) * 4 + b) * 2048 + h * 64 + cb * 8);
      pv2[l] = *(const u16x8*)(vtg + ((size_t)bh * 64 + row) * 2048 + j0 + cb * 8);
    }
  };

  auto loadPPfull = [&](int jc){             // full 128-row window (prologue)
    const int D = jc * 64 - i0;
    #pragma unroll
    for (int l = 0; l < 4; ++l){
      int idx = t + l * 256;
      int row = idx >> 3, cb = idx & 7;
      int pr;
      if (D <= 960)          pr = D + 960 + row;
      else if (D == 1024)    pr = (row < 64) ? (1984 + row) : (row - 65);
      else                   pr = D - 1089 + row;
      u16x8 x;
      if (pr >= 0 && pr < T_){
        x = *(const u16x8*)(pbm + (size_t)pr * 1024 + h * 64 + cb * 8);
      } else {
        for (int j = 0; j < 8; ++j) x[j] = 0;
      }
      pp[l] = x;
    }
  };

  auto loadPPhalf = [&](int jc){             // rows [64,128) of window(jc)
    const int D = jc * 64 - i0;
    #pragma unroll
    for (int l = 0; l < 2; ++l){
      int idx = t + l * 256;
      int rowh = idx >> 3, cb = idx & 7;
      int pr = (D <= 960) ? (D + 1024 + rowh) : (D - 1025 + rowh);
      u16x8 x;
      if (pr >= 0 && pr < T_){
        x = *(const u16x8*)(pbm + (size_t)pr * 1024 + h * 64 + cb * 8);
      } else {
        for (int j = 0; j < 8; ++j) x[j] = 0;
      }
      pp[l] = x;
    }
  };

  auto storeKV = [&](){
    #pragma unroll
    for (int l = 0; l < 2; ++l){
      int idx = t + l * 256;
      int row = idx >> 3, cb = idx & 7;
      int sw = (cb ^ (row & 7)) * 8;
      *(u16x8*)&Kc[row * 64 + sw] = pk[l];
      *(u16x8*)&VT[row * 64 + sw] = pv2[l];
    }
  };
  auto storePPfull = [&](){
    #pragma unroll
    for (int l = 0; l < 4; ++l){
      int idx = t + l * 256;
      int row = idx >> 3, cb = idx & 7;
      *(u16x8*)&Pw[row * 64 + ((cb ^ (row & 7)) * 8)] = pp[l];
    }
  };
  auto storePPhalf = [&](int physh){
    #pragma unroll
    for (int l = 0; l < 2; ++l){
      int idx = t + l * 256;
      int rowh = idx >> 3, cb = idx & 7;
      *(u16x8*)&Pw[(physh * 64 + rowh) * 64 + ((cb ^ (rowh & 7)) * 8)] = pp[l];
    }
  };

  const int jcs = jh * 16, jce = jcs + 16;
  loadKV(jcs);
  loadPPfull(jcs);
  int par = 0;                               // (jc - jcs) & 1

  // per-r bpermute indices & window-select predicates (chunk-invariant)
  int pidx[4];
  bool psel[4];
  #pragma unroll
  for (int r = 0; r < 4; ++r){
    pidx[r] = ((lane & 48) + ((l16 + 15 - 4 * quad - r) & 15)) * 4;
    psel[r] = (l16 + 4 * quad + r) < 15;
  }

  #pragma unroll 1
  for (int jc = jcs; jc < jce; ++jc){
    const int D = jc * 64 - i0;

    __syncthreads();                         // (1) prev chunk's LDS reads done
    storeKV();
    if (jc == jcs) storePPfull(); else storePPhalf(1 ^ par);
    if (jc + 1 < jce){ loadKV(jc + 1); loadPPhalf(jc + 1); }   // prefetch next
    __syncthreads();                         // (2) staging visible

    // ---- pos scores: 5 trimmed windows kept in registers ----
    f32x4 racc5[5];
    #pragma unroll
    for (int ci = 0; ci < 5; ++ci){
      int ct = ctLo + ci;
      int cs = (D <= 960) ? 0 : ((D >= 1088) ? 1 : ((ct >= 4) ? 1 : 0));
      f32x4 racc = {};
      #pragma unroll
      for (int ks = 0; ks < 2; ++ks){
        int rr = ct * 16 + l16;
        int prow = ((rr >> 6) ^ par) * 64 + (rr & 63);
        short8 bf = *(short8*)&Pw[prow * 64 + (((ks * 4 + quad) ^ (rr & 7)) * 8)];
        racc = __builtin_amdgcn_mfma_f32_16x16x32_bf16(qv[cs][ks], bf, racc, 0, 0, 0);
      }
      racc5[ci] = racc;
    }

    // ---- content scores ----
    f32x4 cacc[4] = {};
    #pragma unroll
    for (int ks = 0; ks < 2; ++ks){
      #pragma unroll
      for (int ct = 0; ct < 4; ++ct){
        int rr = ct * 16 + l16;
        short8 bf = *(short8*)&Kc[rr * 64 + (((ks * 4 + quad) ^ (rr & 7)) * 8)];
        cacc[ct] = __builtin_amdgcn_mfma_f32_16x16x32_bf16(qu[ks], bf, cacc[ct], 0, 0, 0);
      }
    }

    // ---- softmax with pack-2 bpermute rel-shift pull (static indices) ----
    #pragma unroll
    for (int r = 0; r < 4; ++r){
      int gm = 16 * w + quad * 4 + r;
      // window selects with COMPILE-TIME racc5 indices (v_cndmask, no scratch)
      float w0 = psel[r] ? racc5[1][r] : racc5[0][r];
      float w1 = psel[r] ? racc5[2][r] : racc5[1][r];
      float w2 = psel[r] ? racc5[3][r] : racc5[2][r];
      float w3 = psel[r] ? racc5[4][r] : racc5[3][r];
      uint32_t pa = (uint32_t)f2bt(w0) | ((uint32_t)f2bt(w1) << 16);
      uint32_t pb = (uint32_t)f2bt(w2) | ((uint32_t)f2bt(w3) << 16);
      uint32_t ra = (uint32_t)__builtin_amdgcn_ds_bpermute(pidx[r], (int)pa);
      uint32_t rb = (uint32_t)__builtin_amdgcn_ds_bpermute(pidx[r], (int)pb);
      float p0 = b2f((unsigned short)(ra & 0xffffu));
      float p1 = b2f((unsigned short)(ra >> 16));
      float p2 = b2f((unsigned short)(rb & 0xffffu));
      float p3 = b2f((unsigned short)(rb >> 16));
      float e0 = __builtin_amdgcn_exp2f(cacc[0][r] + p0 - EOF_);
      float e1 = __builtin_amdgcn_exp2f(cacc[1][r] + p1 - EOF_);
      float e2 = __builtin_amdgcn_exp2f(cacc[2][r] + p2 - EOF_);
      float e3 = __builtin_amdgcn_exp2f(cacc[3][r] + p3 - EOF_);
      lsum[r] += (e0 + e1) + (e2 + e3);
      SP[SP_IX(gm, 0 * 16 + l16)] = f2bt(e0);
      SP[SP_IX(gm, 1 * 16 + l16)] = f2bt(e1);
      SP[SP_IX(gm, 2 * 16 + l16)] = f2bt(e2);
      SP[SP_IX(gm, 3 * 16 + l16)] = f2bt(e3);
    }

    // ---- PV: A-frag from own-wave SP rows, B-frag from swizzled VT ----
    #pragma unroll
    for (int ks = 0; ks < 2; ++ks){
      short8 af = *(short8*)&SP[SP_IX(16 * w + l16, ks * 32 + quad * 8)];
      #pragma unroll
      for (int dt = 0; dt < 4; ++dt){
        int rr = dt * 16 + l16;
        short8 bf = *(short8*)&VT[rr * 64 + (((ks * 4 + quad) ^ (rr & 7)) * 8)];
        oacc[dt] = __builtin_amdgcn_mfma_f32_16x16x32_bf16(af, bf, oacc[dt], 0, 0, 0);
      }
    }

    par ^= 1;
  }

  // ---- epilogue: reduce row sums, store bf16 O-partial + fp32 l-partial ----
  unsigned short* ob = opart + (size_t)jh * 4096 * 1024;
  float* lb = lpart + (size_t)jh * 4096 * 16;
  #pragma unroll
  for (int r = 0; r < 4; ++r){
    float red = lsum[r];
    #pragma unroll
    for (int mk = 1; mk < 16; mk <<= 1)
      red += __shfl_xor(red, mk, 64);
    int srow = i0 + 16 * w + quad * 4 + r;
    int grow = srow * 4 + b;
    #pragma unroll
    for (int dt = 0; dt < 4; ++dt)
      ob[(size_t)grow * 1024 + h * 64 + dt * 16 + l16] = f2bt(oacc[dt][r]);
    if (l16 == 0) lb[(size_t)grow * 16 + h] = red;
  }
}

// ---------------------------------------------------------------------------
// Combine the two j-half partials: awv = (O0 + O1) / (l0 + l1), bf16 out.
// ---------------------------------------------------------------------------
__global__ __launch_bounds__(256) void attn_combine(
    const unsigned short* __restrict__ opart, const float* __restrict__ lpart,
    unsigned short* __restrict__ awvb)
{
  const int grow = blockIdx.x, t = threadIdx.x;
  const int d4 = t * 4, h = t >> 4;
  float l = lpart[(size_t)grow * 16 + h] + lpart[(size_t)4096 * 16 + grow * 16 + h];
  float inv = 1.f / l;
  ushort4 a = *(const ushort4*)(opart + (size_t)grow * 1024 + d4);
  ushort4 c = *(const ushort4*)(opart + (size_t)4096 * 1024 + grow * 1024 + d4);
  ushort4 o;
  o.x = f2bt((b2f(a.x) + b2f(c.x)) * inv);
  o.y = f2bt((b2f(a.y) + b2f(c.y)) * inv);
  o.z = f2bt((b2f(a.z) + b2f(c.z)) * inv);
  o.w = f2bt((b2f(a.w) + b2f(c.w)) * inv);
  *(ushort4*)(awvb + (size_t)grow * 1024 + d4) = o;
}

// ---------------------------------------------------------------------------
// LayerNorm over last dim: out = LN(input + P0 + P1) * g + b  (fp32 out).
// ---------------------------------------------------------------------------
__global__ __launch_bounds__(256) void ln2_kernel(
    const float* __restrict__ inp, const float* __restrict__ OutP,
    const float* __restrict__ g, const float* __restrict__ bb,
    float* __restrict__ out)
{
  const int row = blockIdx.x, t = threadIdx.x;
  float4 x  = *(const float4*)(inp  + (size_t)row * 1024 + t * 4);
  float4 p0 = *(const float4*)(OutP + (size_t)row * 1024 + t * 4);
  float4 p1 = *(const float4*)(OutP + (size_t)4096 * 1024 + row * 1024 + t * 4);
  x.x += p0.x + p1.x; x.y += p0.y + p1.y; x.z += p0.z + p1.z; x.w += p0.w + p1.w;
  float s  = x.x + x.y + x.z + x.w;
  float s2 = x.x*x.x + x.y*x.y + x.z*x.z + x.w*x.w;
  #pragma unroll
  for (int o = 32; o > 0; o >>= 1){
    s  += __shfl_down(s, o);
    s2 += __shfl_down(s2, o);
  }
  __shared__ float rs[4], rs2[4];
  int w = t >> 6, lane = t & 63;
  if (lane == 0){ rs[w] = s; rs2[w] = s2; }
  __syncthreads();
  s  = rs[0] + rs[1] + rs[2] + rs[3];
  s2 = rs2[0] + rs2[1] + rs2[2] + rs2[3];
  float mu   = s * (1.f/1024.f);
  float var  = s2 * (1.f/1024.f) - mu*mu;
  float rstd = rsqrtf(var + 1e-5f);
  float4 gg = *(const float4*)(g + t*4);
  float4 bv = *(const float4*)(bb + t*4);
  float4 o;
  o.x = (x.x - mu)*rstd*gg.x + bv.x;
  o.y = (x.y - mu)*rstd*gg.y + bv.y;
  o.z = (x.z - mu)*rstd*gg.z + bv.z;
  o.w = (x.w - mu)*rstd*gg.w + bv.w;
  *(float4*)(out + (size_t)row * 1024 + t * 4) = o;
}

extern "C" void kernel_launch(void* const* d_in, const int* in_sizes, int n_in,
                              void* d_out, int out_size, void* d_ws, size_t ws_size,
                              hipStream_t stream) {
  (void)in_sizes; (void)n_in; (void)out_size; (void)ws_size;
  const float* input_ = (const float*)d_in[0];
  const float* pos    = (const float*)d_in[1];
  const float* mem    = (const float*)d_in[2];
  const float* u      = (const float*)d_in[3];
  const float* v      = (const float*)d_in[4];
  const float* Wkv    = (const float*)d_in[5];
  const float* Wq     = (const float*)d_in[6];
  const float* Wp     = (const float*)d_in[7];
  const float* Wout   = (const float*)d_in[8];
  const float* lng    = (const float*)d_in[9];
  const float* lnb    = (const float*)d_in[10];
  float* out = (float*)d_out;

  unsigned short* ws   = (unsigned short*)d_ws;
  unsigned short* xb    = ws;                               // 8192*1024
  unsigned short* posb  = xb    + (size_t)8192*1024;        // 2048*1024
  unsigned short* WkvT  = posb  + (size_t)2048*1024;        // 2048*1024
  unsigned short* WqT   = WkvT  + (size_t)2048*1024;        // 1024*1024
  unsigned short* WpT   = WqT   + (size_t)1024*1024;        // 1024*1024
  unsigned short* WoutT = WpT   + (size_t)1024*1024;        // 1024*1024
  unsigned short* kvb   = WoutT + (size_t)1024*1024;        // 8192*2048
  unsigned short* qbb   = kvb   + (size_t)8192*2048;        // 4096*1024
  unsigned short* pbb   = qbb   + (size_t)4096*1024;        // 2048*1024
  unsigned short* vtg   = pbb   + (size_t)2048*1024;        // 4096*2048
  unsigned short* awvb  = vtg   + (size_t)4096*2048;        // 4096*1024

  // overlays (lifetime-disjoint):
  unsigned short* opart = xb;                 // 2 x 4096*1024 bf16; xb dead after gemm_multi
  float*          lpart = (float*)posb;       // 2 x 4096*16 fp32;  posb dead after gemm_multi
  float*          OutP  = (float*)kvb;        // 2 x 4096*1024 fp32; kvb dead after attn

  // fused prep: bf16 converts + all weight transposes in one dispatch
  prep_all<<<15360, 256, 0, stream>>>(mem, input_, pos, Wkv, Wq, Wp, Wout,
                                      xb, posb, WkvT, WqT, WpT, WoutT);

  // merged projections (kv + q + p) in one dispatch
  gemm_multi<<<1408, 256, 0, stream>>>(xb, posb, WkvT, WqT, WpT, kvb, qbb, pbb);

  // V transpose for PV B-operand
  vtrans<<<dim3(32, 64), 256, 0, stream>>>(kvb, vtg);

  // fused rel-shift MFMA flash attention, split-j x2
  attn_mfma<<<dim3(16, 64, 2), 256, 0, stream>>>(qbb, kvb, pbb, vtg, u, v, opart, lpart);
  attn_combine<<<4096, 256, 0, stream>>>(opart, lpart, awvb);

  // out-projection, split-K x2 (fp32 partials), then fused residual+LN
  gemm_outk<<<dim3(8, 32, 2), 256, 0, stream>>>(awvb, WoutT, OutP);
  ln2_kernel<<<4096, 256, 0, stream>>>(input_, OutP, lng, lnb, out);
}

// Round 13
// 368.563 us; speedup vs baseline: 1.4066x; 1.0302x over previous
//
#include <hip/hip_runtime.h>
#include <cstdint>
#include <cstddef>

#define S_  1024
#define B_  4
#define T_  2048
#define H_  16

typedef short     short8 __attribute__((ext_vector_type(8)));
typedef float     f32x4  __attribute__((ext_vector_type(4)));
typedef unsigned short u16x8 __attribute__((ext_vector_type(8)));

__device__ __forceinline__ unsigned short f2b(float f){
  uint32_t x = __builtin_bit_cast(uint32_t, f);
  x = (x + 0x7fffu + ((x >> 16) & 1u)) >> 16;   // RNE
  return (unsigned short)x;
}
__device__ __forceinline__ unsigned short f2bt(float f){   // truncate (1 op)
  return (unsigned short)(__builtin_bit_cast(uint32_t, f) >> 16);
}
__device__ __forceinline__ float b2f(unsigned short u){
  return __builtin_bit_cast(float, ((uint32_t)u) << 16);
}

// async global->LDS, 16B per lane; lds dest must be wave-uniform base
__device__ __forceinline__ void gl_lds16(const unsigned short* g, unsigned short* l){
  __builtin_amdgcn_global_load_lds(
      (const __attribute__((address_space(1))) void*)g,
      (__attribute__((address_space(3))) void*)l,
      16, 0, 0);
}

// ---------------------------------------------------------------------------
// Fused prep: fp32->bf16 converts (x_mem, pos) AND all 4 weight transposes
// in ONE dispatch (block-uniform branch). blk<10240: cvt; else wtrans.
// ---------------------------------------------------------------------------
__global__ __launch_bounds__(256) void prep_all(
    const float* __restrict__ memsrc, const float* __restrict__ inp,
    const float* __restrict__ pos,
    const float* __restrict__ Wkv, const float* __restrict__ Wq,
    const float* __restrict__ Wp,  const float* __restrict__ Wout,
    unsigned short* __restrict__ xb, unsigned short* __restrict__ posb,
    unsigned short* __restrict__ WkvT, unsigned short* __restrict__ WqT,
    unsigned short* __restrict__ WpT,  unsigned short* __restrict__ WoutT)
{
  __shared__ float tile[32][33];
  int blk = blockIdx.x;
  if (blk < 10240){
    int i = (blk * 256 + threadIdx.x) * 4;
    const float* src;
    unsigned short* dst;
    if (i < 8192 * 1024){
      src = (i < 4096 * 1024) ? (memsrc + i) : (inp + (i - 4096 * 1024));
      dst = xb + i;
    } else {
      int i2 = i - 8192 * 1024;
      src = pos + i2;
      dst = posb + i2;
    }
    float4 x = *(const float4*)src;
    ushort4 o;
    o.x = f2b(x.x); o.y = f2b(x.y); o.z = f2b(x.z); o.w = f2b(x.w);
    *(ushort4*)dst = o;
    return;
  }
  blk -= 10240;
  const float* in; unsigned short* out; int C, bx, by;
  if (blk < 2048){ in = Wkv; out = WkvT; C = 2048; bx = blk & 63; by = blk >> 6; }
  else {
    int r = blk - 2048; int wi = r >> 10; r &= 1023;
    C = 1024; bx = r & 31; by = r >> 5;
    in  = (wi == 0) ? Wq  : ((wi == 1) ? Wp  : Wout);
    out = (wi == 0) ? WqT : ((wi == 1) ? WpT : WoutT);
  }
  const int R0 = by * 32, C0 = bx * 32;
  const int t = threadIdx.x;
  const int r = t >> 3, c4 = (t & 7) * 4;
  float4 x = *(const float4*)(in + (size_t)(R0 + r) * C + C0 + c4);
  tile[r][c4+0] = x.x; tile[r][c4+1] = x.y; tile[r][c4+2] = x.z; tile[r][c4+3] = x.w;
  __syncthreads();
  ushort4 o;
  o.x = f2b(tile[c4+0][r]); o.y = f2b(tile[c4+1][r]);
  o.z = f2b(tile[c4+2][r]); o.w = f2b(tile[c4+3][r]);
  *(ushort4*)(out + (size_t)(C0 + r) * 1024 + R0 + c4) = o;
}

// ---------------------------------------------------------------------------
// Transpose V-half of kv into VTg[bh*64 + d][T] (bf16) for PV B-operand.
// ---------------------------------------------------------------------------
__global__ __launch_bounds__(256) void vtrans(
    const unsigned short* __restrict__ kvb, unsigned short* __restrict__ vtg)
{
  __shared__ __align__(16) unsigned short tile[64][72];
  const int t = threadIdx.x;
  const int bh = blockIdx.y;           // b*16+h
  const int b = bh >> 4, h = bh & 15;
  const int t0 = blockIdx.x * 64;
  #pragma unroll
  for (int l = 0; l < 2; ++l){
    int idx = t + l * 256;
    int row = idx >> 3, seg = (idx & 7) * 8;
    u16x8 x = *(const u16x8*)(kvb + ((size_t)(t0 + row) * 4 + b) * 2048 + 1024 + h * 64 + seg);
    *(u16x8*)&tile[row][seg] = x;
  }
  __syncthreads();
  #pragma unroll
  for (int l = 0; l < 2; ++l){
    int idx = t + l * 256;
    int d = idx >> 3, nseg = (idx & 7) * 8;
    u16x8 o;
    #pragma unroll
    for (int j = 0; j < 8; ++j) o[j] = tile[nseg + j][d];
    *(u16x8*)(vtg + ((size_t)bh * 64 + d) * 2048 + t0 + nseg) = o;
  }
}

// LDS layout for async-staged GEMM tiles (m97 pattern, width=16)
#define AS_IDX(row,k) ((((row) >> 3) * 512) + (((k) >> 3) * 64) + (((row) & 7) * 8) + ((k) & 7))

// ---------------------------------------------------------------------------
// Merged projection GEMM: kv (1024 blocks) + q (256) + p (128) in ONE
// dispatch. XCD-aware bijective swizzle (1408 = 8 XCD x 176).
// ---------------------------------------------------------------------------
__global__ __launch_bounds__(256) void gemm_multi(
    const unsigned short* __restrict__ xb,   // (8192,1024)
    const unsigned short* __restrict__ posb, // (2048,1024)
    const unsigned short* __restrict__ WkvT, // (2048,1024)
    const unsigned short* __restrict__ WqT,  // (1024,1024)
    const unsigned short* __restrict__ WpT,  // (1024,1024)
    unsigned short* __restrict__ kvb,        // (8192,2048)
    unsigned short* __restrict__ qbb,        // (4096,1024)
    unsigned short* __restrict__ pbb)        // (2048,1024)
{
  const unsigned short *A, *BT;
  unsigned short* C;
  int N, local;
  int bx = (blockIdx.x & 7) * 176 + (blockIdx.x >> 3);   // XCD swizzle, bijective on [0,1408)
  if (bx < 1024){       A = xb;                       BT = WkvT; C = kvb; N = 2048; local = bx;        }
  else if (bx < 1280){  A = xb + (size_t)4096 * 1024; BT = WqT;  C = qbb; N = 1024; local = bx - 1024; }
  else {                A = posb;                     BT = WpT;  C = pbb; N = 1024; local = bx - 1280; }
  const int nb = N >> 7;
  const int M0 = (local / nb) * 128, N0 = (local % nb) * 128;
  const int K = 1024;

  __shared__ __align__(16) unsigned short As[128 * 64];
  __shared__ __align__(16) unsigned short Bs[128 * 64];
  const int t = threadIdx.x;
  const int w = t >> 6, lane = t & 63, quad = lane >> 4, l16 = lane & 15;
  const int wm = (w >> 1) * 64, wn = (w & 1) * 64;
  const int lr = lane & 7, lcb = lane >> 3;

  f32x4 acc[4][4] = {};

  for (int k0 = 0; k0 < K; k0 += 64){
    __syncthreads();
    #pragma unroll
    for (int i = 0; i < 4; ++i){
      int blk = 4 * w + i;
      gl_lds16(A  + (size_t)(M0 + 8 * blk + lr) * K + k0 + lcb * 8, As + blk * 512);
      gl_lds16(BT + (size_t)(N0 + 8 * blk + lr) * K + k0 + lcb * 8, Bs + blk * 512);
    }
    __syncthreads();
    #pragma unroll
    for (int ks = 0; ks < 2; ++ks){
      short8 af[4], bf[4];
      #pragma unroll
      for (int rt = 0; rt < 4; ++rt)
        af[rt] = *(short8*)&As[AS_IDX(wm + rt * 16 + l16, ks * 32 + quad * 8)];
      #pragma unroll
      for (int ct = 0; ct < 4; ++ct)
        bf[ct] = *(short8*)&Bs[AS_IDX(wn + ct * 16 + l16, ks * 32 + quad * 8)];
      #pragma unroll
      for (int rt = 0; rt < 4; ++rt)
        #pragma unroll
        for (int ct = 0; ct < 4; ++ct)
          acc[rt][ct] = __builtin_amdgcn_mfma_f32_16x16x32_bf16(af[rt], bf[ct], acc[rt][ct], 0, 0, 0);
    }
  }

  #pragma unroll
  for (int rt = 0; rt < 4; ++rt)
    #pragma unroll
    for (int r = 0; r < 4; ++r){
      int row = M0 + wm + rt * 16 + quad * 4 + r;
      #pragma unroll
      for (int ct = 0; ct < 4; ++ct)
        C[(size_t)row * N + N0 + wn + ct * 16 + l16] = f2b(acc[rt][ct][r]);
    }
}

// ---------------------------------------------------------------------------
// Out-projection GEMM, split-K x2. Grid (8,32,2) linearized + XCD swizzle.
// ---------------------------------------------------------------------------
__global__ __launch_bounds__(256) void gemm_outk(
    const unsigned short* __restrict__ A,    // awvb (4096,1024)
    const unsigned short* __restrict__ BT,   // WoutT (1024,1024)
    float* __restrict__ OutP)                // 2 x (4096,1024) fp32
{
  const int K = 1024, N = 1024;
  int lid = blockIdx.x + 8 * (blockIdx.y + 32 * blockIdx.z);   // [0,512)
  int sw  = (lid & 7) * 64 + (lid >> 3);                        // XCD swizzle
  const int N0 = (sw & 7) * 128;
  const int M0 = ((sw >> 3) & 31) * 128;
  const int kz = sw >> 8;
  const int k0s = kz * 512, k0e = k0s + 512;
  float* outF = OutP + (size_t)kz * 4096 * 1024;

  __shared__ __align__(16) unsigned short As[128 * 64];
  __shared__ __align__(16) unsigned short Bs[128 * 64];
  const int t = threadIdx.x;
  const int w = t >> 6, lane = t & 63, quad = lane >> 4, l16 = lane & 15;
  const int wm = (w >> 1) * 64, wn = (w & 1) * 64;
  const int lr = lane & 7, lcb = lane >> 3;

  f32x4 acc[4][4] = {};

  for (int k0 = k0s; k0 < k0e; k0 += 64){
    __syncthreads();
    #pragma unroll
    for (int i = 0; i < 4; ++i){
      int blk = 4 * w + i;
      gl_lds16(A  + (size_t)(M0 + 8 * blk + lr) * K + k0 + lcb * 8, As + blk * 512);
      gl_lds16(BT + (size_t)(N0 + 8 * blk + lr) * K + k0 + lcb * 8, Bs + blk * 512);
    }
    __syncthreads();
    #pragma unroll
    for (int ks = 0; ks < 2; ++ks){
      short8 af[4], bf[4];
      #pragma unroll
      for (int rt = 0; rt < 4; ++rt)
        af[rt] = *(short8*)&As[AS_IDX(wm + rt * 16 + l16, ks * 32 + quad * 8)];
      #pragma unroll
      for (int ct = 0; ct < 4; ++ct)
        bf[ct] = *(short8*)&Bs[AS_IDX(wn + ct * 16 + l16, ks * 32 + quad * 8)];
      #pragma unroll
      for (int rt = 0; rt < 4; ++rt)
        #pragma unroll
        for (int ct = 0; ct < 4; ++ct)
          acc[rt][ct] = __builtin_amdgcn_mfma_f32_16x16x32_bf16(af[rt], bf[ct], acc[rt][ct], 0, 0, 0);
    }
  }

  #pragma unroll
  for (int rt = 0; rt < 4; ++rt)
    #pragma unroll
    for (int r = 0; r < 4; ++r){
      int row = M0 + wm + rt * 16 + quad * 4 + r;
      #pragma unroll
      for (int ct = 0; ct < 4; ++ct)
        outF[(size_t)row * N + N0 + wn + ct * 16 + l16] = acc[rt][ct][r];
    }
}

// ---------------------------------------------------------------------------
// MFMA flash attention, fused Transformer-XL rel-shift, split-j x2.
// R10 structure (best measured: 139.2us — the pack-2 variant R12 was a
// null: -8 bpermutes offset by +packing VALU). One 16-value-per-r bpermute
// pull for the rel-shift; SP holds only the exp(P) buffer for PV A-frags
// (LDS is the right crossbar for that all-to-all; bpermute isn't).
// Added: T5 s_setprio(1) around the MFMA clusters (+4-7% on attn, m191;
// waves here have role diversity between barriers via trimmed pos windows).
// LDS = 8K (Kc) + 8K (VT) + 16K (Pw) + 8K (SP) = 40960 B.
// __launch_bounds__(256,3): VGPR 84, no scratch ((256,4) spills).
// ---------------------------------------------------------------------------
#define SP_IX(gm,n) ((gm) * 64 + ((n) ^ (((gm) & 12) << 2)))

__global__ __launch_bounds__(256, 3) void attn_mfma(
    const unsigned short* __restrict__ qb,   // (4096,1024) bf16
    const unsigned short* __restrict__ kvb,  // (8192,2048) bf16 [k|v]
    const unsigned short* __restrict__ pbm,  // (2048,1024) bf16
    const unsigned short* __restrict__ vtg,  // (64*64, 2048) bf16 V^T per (b,h)
    const float* __restrict__ ub, const float* __restrict__ vb,
    unsigned short* __restrict__ opart,      // 2 x (4096,1024) bf16 partials
    float* __restrict__ lpart)               // 2 x (4096,16) fp32 partials
{
  __shared__ __align__(16) unsigned short Kc[64 * 64];   // swizzled K tile
  __shared__ __align__(16) unsigned short VT[64 * 64];   // swizzled V^T tile
  __shared__ __align__(16) unsigned short Pw[128 * 64];  // swizzled pos ring (2 halves)
  __shared__ __align__(16) unsigned short SP[64 * 64];   // P (exp) buffer, swizzled

  const int t = threadIdx.x;
  const int i0 = blockIdx.x * 64;
  const int bh = blockIdx.y;
  const int jh = blockIdx.z;
  const int b = bh >> 4, h = bh & 15;
  const int w = t >> 6, lane = t & 63, quad = lane >> 4, l16 = lane & 15;
  const int colbase = h * 64 + quad * 8;
  const int ctLo = 3 - w;                    // wave-trimmed window range [ctLo, ctLo+4]

  const float SCQ = 0.1803368801f;           // 0.125 * log2(e)
  const float EOF_ = 23.0831206f;            // 16 * log2(e)

  // ---- register A-fragments: qu[ks], qv[cs][ks], pre-scaled by SCQ ----
  short8 qu[2], qv[2][2];
  #pragma unroll
  for (int cs = 0; cs < 2; ++cs){
    int gr = i0 + 16 * w + l16 + cs;         // gr==1024 possible: harmless
    #pragma unroll
    for (int ks = 0; ks < 2; ++ks){
      u16x8 q8 = *(const u16x8*)(qb + ((size_t)gr * 4 + b) * 1024 + colbase + ks * 32);
      #pragma unroll
      for (int j = 0; j < 8; ++j){
        float f = b2f(q8[j]);
        qv[cs][ks][j] = (short)f2b((f + vb[colbase + ks * 32 + j]) * SCQ);
        if (cs == 0) qu[ks][j] = (short)f2b((f + ub[colbase + ks * 32 + j]) * SCQ);
      }
    }
  }

  f32x4 oacc[4] = {};                        // [d-tile], rows = quad*4+r
  float lsum[4] = {0.f, 0.f, 0.f, 0.f};

  // staging prefetch registers
  u16x8 pk[2], pv2[2], pp[4];

  auto loadKV = [&](int jc){
    const int j0 = jc * 64;
    #pragma unroll
    for (int l = 0; l < 2; ++l){
      int idx = t + l * 256;
      int row = idx >> 3, cb = idx & 7;
      pk[l]  = *(const u16x8*)(kvb + ((size_t)(j0 + row) * 4 + b) * 2048 + h * 64 + cb * 8);
      pv2[l] = *(const u16x8*)(vtg + ((size_t)bh * 64 + row) * 2048 + j0 + cb * 8);
    }
  };

  auto loadPPfull = [&](int jc){             // full 128-row window (prologue)
    const int D = jc * 64 - i0;
    #pragma unroll
    for (int l = 0; l < 4; ++l){
      int idx = t + l * 256;
      int row = idx >> 3, cb = idx & 7;
      int pr;
      if (D <= 960)          pr = D + 960 + row;
      else if (D == 1024)    pr = (row < 64) ? (1984 + row) : (row - 65);
      else                   pr = D - 1089 + row;
      u16x8 x;
      if (pr >= 0 && pr < T_){
        x = *(const u16x8*)(pbm + (size_t)pr * 1024 + h * 64 + cb * 8);
      } else {
        for (int j = 0; j < 8; ++j) x[j] = 0;
      }
      pp[l] = x;
    }
  };

  auto loadPPhalf = [&](int jc){             // rows [64,128) of window(jc)
    const int D = jc * 64 - i0;
    #pragma unroll
    for (int l = 0; l < 2; ++l){
      int idx = t + l * 256;
      int rowh = idx >> 3, cb = idx & 7;
      int pr = (D <= 960) ? (D + 1024 + rowh) : (D - 1025 + rowh);
      u16x8 x;
      if (pr >= 0 && pr < T_){
        x = *(const u16x8*)(pbm + (size_t)pr * 1024 + h * 64 + cb * 8);
      } else {
        for (int j = 0; j < 8; ++j) x[j] = 0;
      }
      pp[l] = x;
    }
  };

  auto storeKV = [&](){
    #pragma unroll
    for (int l = 0; l < 2; ++l){
      int idx = t + l * 256;
      int row = idx >> 3, cb = idx & 7;
      int sw = (cb ^ (row & 7)) * 8;
      *(u16x8*)&Kc[row * 64 + sw] = pk[l];
      *(u16x8*)&VT[row * 64 + sw] = pv2[l];
    }
  };
  auto storePPfull = [&](){
    #pragma unroll
    for (int l = 0; l < 4; ++l){
      int idx = t + l * 256;
      int row = idx >> 3, cb = idx & 7;
      *(u16x8*)&Pw[row * 64 + ((cb ^ (row & 7)) * 8)] = pp[l];
    }
  };
  auto storePPhalf = [&](int physh){
    #pragma unroll
    for (int l = 0; l < 2; ++l){
      int idx = t + l * 256;
      int rowh = idx >> 3, cb = idx & 7;
      *(u16x8*)&Pw[(physh * 64 + rowh) * 64 + ((cb ^ (rowh & 7)) * 8)] = pp[l];
    }
  };

  const int jcs = jh * 16, jce = jcs + 16;
  loadKV(jcs);
  loadPPfull(jcs);
  int par = 0;                               // (jc - jcs) & 1

  // per-r bpermute indices & window-select predicates (chunk-invariant)
  int pidx[4];
  bool psel[4];
  #pragma unroll
  for (int r = 0; r < 4; ++r){
    pidx[r] = ((lane & 48) + ((l16 + 15 - 4 * quad - r) & 15)) * 4;
    psel[r] = (l16 + 4 * quad + r) < 15;
  }

  #pragma unroll 1
  for (int jc = jcs; jc < jce; ++jc){
    const int D = jc * 64 - i0;

    __syncthreads();                         // (1) prev chunk's LDS reads done
    storeKV();
    if (jc == jcs) storePPfull(); else storePPhalf(1 ^ par);
    if (jc + 1 < jce){ loadKV(jc + 1); loadPPhalf(jc + 1); }   // prefetch next
    __syncthreads();                         // (2) staging visible

    // ---- pos scores: 5 trimmed windows kept in registers ----
    f32x4 racc5[5];
    __builtin_amdgcn_s_setprio(1);
    #pragma unroll
    for (int ci = 0; ci < 5; ++ci){
      int ct = ctLo + ci;
      int cs = (D <= 960) ? 0 : ((D >= 1088) ? 1 : ((ct >= 4) ? 1 : 0));
      f32x4 racc = {};
      #pragma unroll
      for (int ks = 0; ks < 2; ++ks){
        int rr = ct * 16 + l16;
        int prow = ((rr >> 6) ^ par) * 64 + (rr & 63);
        short8 bf = *(short8*)&Pw[prow * 64 + (((ks * 4 + quad) ^ (rr & 7)) * 8)];
        racc = __builtin_amdgcn_mfma_f32_16x16x32_bf16(qv[cs][ks], bf, racc, 0, 0, 0);
      }
      racc5[ci] = racc;
    }
    __builtin_amdgcn_s_setprio(0);

    // ---- content scores ----
    f32x4 cacc[4] = {};
    __builtin_amdgcn_s_setprio(1);
    #pragma unroll
    for (int ks = 0; ks < 2; ++ks){
      #pragma unroll
      for (int ct = 0; ct < 4; ++ct){
        int rr = ct * 16 + l16;
        short8 bf = *(short8*)&Kc[rr * 64 + (((ks * 4 + quad) ^ (rr & 7)) * 8)];
        cacc[ct] = __builtin_amdgcn_mfma_f32_16x16x32_bf16(qu[ks], bf, cacc[ct], 0, 0, 0);
      }
    }
    __builtin_amdgcn_s_setprio(0);

    // ---- softmax with in-register rel-shift pull (ds_bpermute) ----
    #pragma unroll
    for (int r = 0; r < 4; ++r){
      int gm = 16 * w + quad * 4 + r;
      #pragma unroll
      for (int ct = 0; ct < 4; ++ct){
        float selv = psel[r] ? racc5[ct + 1][r] : racc5[ct][r];
        float posv = __builtin_bit_cast(float,
            __builtin_amdgcn_ds_bpermute(pidx[r], __builtin_bit_cast(int, selv)));
        float s = cacc[ct][r] + posv;
        float e = __builtin_amdgcn_exp2f(s - EOF_);
        lsum[r] += e;
        SP[SP_IX(gm, ct * 16 + l16)] = f2bt(e);
      }
    }

    // ---- PV: A-frag from own-wave SP rows, B-frag from swizzled VT ----
    __builtin_amdgcn_s_setprio(1);
    #pragma unroll
    for (int ks = 0; ks < 2; ++ks){
      short8 af = *(short8*)&SP[SP_IX(16 * w + l16, ks * 32 + quad * 8)];
      #pragma unroll
      for (int dt = 0; dt < 4; ++dt){
        int rr = dt * 16 + l16;
        short8 bf = *(short8*)&VT[rr * 64 + (((ks * 4 + quad) ^ (rr & 7)) * 8)];
        oacc[dt] = __builtin_amdgcn_mfma_f32_16x16x32_bf16(af, bf, oacc[dt], 0, 0, 0);
      }
    }
    __builtin_amdgcn_s_setprio(0);

    par ^= 1;
  }

  // ---- epilogue: reduce row sums, store bf16 O-partial + fp32 l-partial ----
  unsigned short* ob = opart + (size_t)jh * 4096 * 1024;
  float* lb = lpart + (size_t)jh * 4096 * 16;
  #pragma unroll
  for (int r = 0; r < 4; ++r){
    float red = lsum[r];
    #pragma unroll
    for (int mk = 1; mk < 16; mk <<= 1)
      red += __shfl_xor(red, mk, 64);
    int srow = i0 + 16 * w + quad * 4 + r;
    int grow = srow * 4 + b;
    #pragma unroll
    for (int dt = 0; dt < 4; ++dt)
      ob[(size_t)grow * 1024 + h * 64 + dt * 16 + l16] = f2bt(oacc[dt][r]);
    if (l16 == 0) lb[(size_t)grow * 16 + h] = red;
  }
}

// ---------------------------------------------------------------------------
// Combine the two j-half partials: awv = (O0 + O1) / (l0 + l1), bf16 out.
// ---------------------------------------------------------------------------
__global__ __launch_bounds__(256) void attn_combine(
    const unsigned short* __restrict__ opart, const float* __restrict__ lpart,
    unsigned short* __restrict__ awvb)
{
  const int grow = blockIdx.x, t = threadIdx.x;
  const int d4 = t * 4, h = t >> 4;
  float l = lpart[(size_t)grow * 16 + h] + lpart[(size_t)4096 * 16 + grow * 16 + h];
  float inv = 1.f / l;
  ushort4 a = *(const ushort4*)(opart + (size_t)grow * 1024 + d4);
  ushort4 c = *(const ushort4*)(opart + (size_t)4096 * 1024 + grow * 1024 + d4);
  ushort4 o;
  o.x = f2bt((b2f(a.x) + b2f(c.x)) * inv);
  o.y = f2bt((b2f(a.y) + b2f(c.y)) * inv);
  o.z = f2bt((b2f(a.z) + b2f(c.z)) * inv);
  o.w = f2bt((b2f(a.w) + b2f(c.w)) * inv);
  *(ushort4*)(awvb + (size_t)grow * 1024 + d4) = o;
}

// ---------------------------------------------------------------------------
// LayerNorm over last dim: out = LN(input + P0 + P1) * g + b  (fp32 out).
// ---------------------------------------------------------------------------
__global__ __launch_bounds__(256) void ln2_kernel(
    const float* __restrict__ inp, const float* __restrict__ OutP,
    const float* __restrict__ g, const float* __restrict__ bb,
    float* __restrict__ out)
{
  const int row = blockIdx.x, t = threadIdx.x;
  float4 x  = *(const float4*)(inp  + (size_t)row * 1024 + t * 4);
  float4 p0 = *(const float4*)(OutP + (size_t)row * 1024 + t * 4);
  float4 p1 = *(const float4*)(OutP + (size_t)4096 * 1024 + row * 1024 + t * 4);
  x.x += p0.x + p1.x; x.y += p0.y + p1.y; x.z += p0.z + p1.z; x.w += p0.w + p1.w;
  float s  = x.x + x.y + x.z + x.w;
  float s2 = x.x*x.x + x.y*x.y + x.z*x.z + x.w*x.w;
  #pragma unroll
  for (int o = 32; o > 0; o >>= 1){
    s  += __shfl_down(s, o);
    s2 += __shfl_down(s2, o);
  }
  __shared__ float rs[4], rs2[4];
  int w = t >> 6, lane = t & 63;
  if (lane == 0){ rs[w] = s; rs2[w] = s2; }
  __syncthreads();
  s  = rs[0] + rs[1] + rs[2] + rs[3];
  s2 = rs2[0] + rs2[1] + rs2[2] + rs2[3];
  float mu   = s * (1.f/1024.f);
  float var  = s2 * (1.f/1024.f) - mu*mu;
  float rstd = rsqrtf(var + 1e-5f);
  float4 gg = *(const float4*)(g + t*4);
  float4 bv = *(const float4*)(bb + t*4);
  float4 o;
  o.x = (x.x - mu)*rstd*gg.x + bv.x;
  o.y = (x.y - mu)*rstd*gg.y + bv.y;
  o.z = (x.z - mu)*rstd*gg.z + bv.z;
  o.w = (x.w - mu)*rstd*gg.w + bv.w;
  *(float4*)(out + (size_t)row * 1024 + t * 4) = o;
}

extern "C" void kernel_launch(void* const* d_in, const int* in_sizes, int n_in,
                              void* d_out, int out_size, void* d_ws, size_t ws_size,
                              hipStream_t stream) {
  (void)in_sizes; (void)n_in; (void)out_size; (void)ws_size;
  const float* input_ = (const float*)d_in[0];
  const float* pos    = (const float*)d_in[1];
  const float* mem    = (const float*)d_in[2];
  const float* u      = (const float*)d_in[3];
  const float* v      = (const float*)d_in[4];
  const float* Wkv    = (const float*)d_in[5];
  const float* Wq     = (const float*)d_in[6];
  const float* Wp     = (const float*)d_in[7];
  const float* Wout   = (const float*)d_in[8];
  const float* lng    = (const float*)d_in[9];
  const float* lnb    = (const float*)d_in[10];
  float* out = (float*)d_out;

  unsigned short* ws   = (unsigned short*)d_ws;
  unsigned short* xb    = ws;                               // 8192*1024
  unsigned short* posb  = xb    + (size_t)8192*1024;        // 2048*1024
  unsigned short* WkvT  = posb  + (size_t)2048*1024;        // 2048*1024
  unsigned short* WqT   = WkvT  + (size_t)2048*1024;        // 1024*1024
  unsigned short* WpT   = WqT   + (size_t)1024*1024;        // 1024*1024
  unsigned short* WoutT = WpT   + (size_t)1024*1024;        // 1024*1024
  unsigned short* kvb   = WoutT + (size_t)1024*1024;        // 8192*2048
  unsigned short* qbb   = kvb   + (size_t)8192*2048;        // 4096*1024
  unsigned short* pbb   = qbb   + (size_t)4096*1024;        // 2048*1024
  unsigned short* vtg   = pbb   + (size_t)2048*1024;        // 4096*2048
  unsigned short* awvb  = vtg   + (size_t)4096*2048;        // 4096*1024

  // overlays (lifetime-disjoint):
  unsigned short* opart = xb;                 // 2 x 4096*1024 bf16; xb dead after gemm_multi
  float*          lpart = (float*)posb;       // 2 x 4096*16 fp32;  posb dead after gemm_multi
  float*          OutP  = (float*)kvb;        // 2 x 4096*1024 fp32; kvb dead after attn

  // fused prep: bf16 converts + all weight transposes in one dispatch
  prep_all<<<15360, 256, 0, stream>>>(mem, input_, pos, Wkv, Wq, Wp, Wout,
                                      xb, posb, WkvT, WqT, WpT, WoutT);

  // merged projections (kv + q + p) in one dispatch
  gemm_multi<<<1408, 256, 0, stream>>>(xb, posb, WkvT, WqT, WpT, kvb, qbb, pbb);

  // V transpose for PV B-operand
  vtrans<<<dim3(32, 64), 256, 0, stream>>>(kvb, vtg);

  // fused rel-shift MFMA flash attention, split-j x2
  attn_mfma<<<dim3(16, 64, 2), 256, 0, stream>>>(qbb, kvb, pbb, vtg, u, v, opart, lpart);
  attn_combine<<<4096, 256, 0, stream>>>(opart, lpart, awvb);

  // out-projection, split-K x2 (fp32 partials), then fused residual+LN
  gemm_outk<<<dim3(8, 32, 2), 256, 0, stream>>>(awvb, WoutT, OutP);
  ln2_kernel<<<4096, 256, 0, stream>>>(input_, OutP, lng, lnb, out);
}